// Round 1
// baseline (138.032 us; speedup 1.0000x reference)
//
#include <hip/hip_runtime.h>
#include <stdint.h>

#define N_ROWS 32768
#define D_CLS  1000
#define D_PAD  1024
#define F_DIM  300
#define F_PAD  320
#define MARGIN 0.1f

// ---- persistent-A GEMM params (K1) ----
#define BM     128
#define BN     128
#define BK     64
#define GTHR   512           // 8 waves: 4 M-groups x 2 N-groups
#define LDTA   328           // A LDS row stride (300 + 28 pad, 16B aligned)
#define LDTB   72            // B LDS row stride (64 + 8 pad)

// ---- fused fallback params ----
#define M_PB   32
#define NTHR   512
#define NT_PW  8
#define MT_PB  2
#define LDA    328
#define SROW   34

#define NPART  32            // reduce stage-1 blocks

typedef short short8 __attribute__((ext_vector_type(8)));
typedef float f32x4  __attribute__((ext_vector_type(4)));

__device__ __forceinline__ uint32_t rotl32(uint32_t x, int r) {
  return (x << r) | (x >> (32 - r));
}

// JAX threefry2x32 (20 rounds) — bit-exact
__device__ __forceinline__ void threefry2x32(uint32_t k0, uint32_t k1,
                                             uint32_t x0, uint32_t x1,
                                             uint32_t& o0, uint32_t& o1) {
  uint32_t k2 = k0 ^ k1 ^ 0x1BD11BDAu;
  x0 += k0; x1 += k1;
#define TF_R(r) { x0 += x1; x1 = rotl32(x1, (r)); x1 ^= x0; }
  TF_R(13) TF_R(15) TF_R(26) TF_R(6)
  x0 += k1; x1 += k2 + 1u;
  TF_R(17) TF_R(29) TF_R(16) TF_R(24)
  x0 += k2; x1 += k0 + 2u;
  TF_R(13) TF_R(15) TF_R(26) TF_R(6)
  x0 += k0; x1 += k1 + 3u;
  TF_R(17) TF_R(29) TF_R(16) TF_R(24)
  x0 += k1; x1 += k2 + 4u;
  TF_R(13) TF_R(15) TF_R(26) TF_R(6)
  x0 += k2; x1 += k0 + 5u;
#undef TF_R
  o0 = x0; o1 = x1;
}

// Hoisted-schedule threefry (r17-verified): same bits, keys precomputed once,
// rotates via v_alignbit_b32. In the fused keygen, the row-pair is WAVE-UNIFORM
// per step so the whole TFSched lives in SGPRs (zero VALU setup cost).
struct TFSched {
  uint32_t k0, k1, k2, k2p1, k0p2, k1p3, k2p4, k0p5;
};
__device__ __forceinline__ TFSched tf_make(uint32_t k0, uint32_t k1) {
  TFSched s;
  s.k0 = k0; s.k1 = k1;
  s.k2 = k0 ^ k1 ^ 0x1BD11BDAu;
  s.k2p1 = s.k2 + 1u; s.k0p2 = k0 + 2u; s.k1p3 = k1 + 3u;
  s.k2p4 = s.k2 + 4u; s.k0p5 = k0 + 5u;
  return s;
}
__device__ __forceinline__ uint32_t tf_hash(const TFSched& s, uint32_t c) {
  uint32_t x0 = s.k0, x1 = c + s.k1;
#define TFH(r) { x0 += x1; x1 = __builtin_amdgcn_alignbit(x1, x1, 32 - (r)); x1 ^= x0; }
  TFH(13) TFH(15) TFH(26) TFH(6)
  x0 += s.k1; x1 += s.k2p1;
  TFH(17) TFH(29) TFH(16) TFH(24)
  x0 += s.k2; x1 += s.k0p2;
  TFH(13) TFH(15) TFH(26) TFH(6)
  x0 += s.k0; x1 += s.k1p3;
  TFH(17) TFH(29) TFH(16) TFH(24)
  x0 += s.k1; x1 += s.k2p4;
  TFH(13) TFH(15) TFH(26) TFH(6)
  x0 += s.k2; x1 += s.k0p5;
#undef TFH
  return x0 ^ x1;
}

__device__ __forceinline__ uint16_t f2bf(float f) {   // RNE fp32 -> bf16
  uint32_t u = __builtin_bit_cast(uint32_t, f);
  return (uint16_t)((u + 0x7FFFu + ((u >> 16) & 1u)) >> 16);
}
__device__ __forceinline__ float bf2f(uint16_t v) {
  return __builtin_bit_cast(float, (uint32_t)v << 16);
}
__device__ __forceinline__ float bf2f_lo(uint32_t v) {
  return __builtin_bit_cast(float, v << 16);
}
__device__ __forceinline__ float bf2f_hi(uint32_t v) {
  return __builtin_bit_cast(float, v & 0xFFFF0000u);
}

// prep: Y fp32 -> Ybf bf16 (zero-padded) AND per-row subkeys (merged kernels)
__global__ void prep(const float* __restrict__ Y, uint16_t* __restrict__ Ybf,
                     uint32_t* __restrict__ subk) {
  int i = blockIdx.x * 256 + threadIdx.x;
  if (i < D_PAD * F_PAD) {
    int j = i / F_PAD;
    int k = i - j * F_PAD;
    float v = (j < D_CLS && k < F_DIM) ? Y[j * F_DIM + k] : 0.f;
    Ybf[i] = f2bf(v);
  }
  if (i < N_ROWS) {
    uint32_t r1, r2, s1, s2;
    threefry2x32(0u, 42u, 0u, (uint32_t)i, r1, r2);
    threefry2x32(r1, r2, 0u, 1u, s1, s2);
    subk[2 * i]     = s1;
    subk[2 * i + 1] = s2;
  }
}

// ====== K1: persistent-A MFMA GEMM, optionally fused with keygen + loss ======
// FUSED=1: while the MFMA main loop runs, idle VALU slots compute the threefry
// top16 keys for the block's 64 row-pairs (wave-uniform row-pair per step ->
// key schedule in SGPRs; per-lane variable is only the column counter).
// Keys pack lo16=rowA/hi16=rowB into keyP[rp][col].  After the loop + barrier
// the block does the (hash-free) loss phases on its own L2-hot Spair/keyP.
// Exactness: min(k)>>16 == min(k>>16) (monotone), so 16-bit phase-1 min is
// bit-identical to the shipped full-32-bit-min + top16-strict-compare kernel.
template<int FUSED>
__launch_bounds__(GTHR, 1)
__global__ void gemm_core(const float* __restrict__ inputs,
                          const uint16_t* __restrict__ Ybf,
                          uint32_t* __restrict__ Spair,
                          uint32_t* __restrict__ keyP,
                          const uint32_t* __restrict__ subk,
                          const int* __restrict__ yidx,
                          float* __restrict__ rowSum,
                          int* __restrict__ rowCnt) {
  __shared__ __align__(16) uint16_t A_lds[BM * LDTA];     // 83,968 B
  __shared__ __align__(16) uint16_t B_lds[2][BN * LDTB];  // 36,864 B

  const int t    = threadIdx.x;
  const int wave = t >> 6;
  const int lane = t & 63;
  const int l15  = lane & 15;
  const int g    = lane >> 4;
  const int wm   = wave >> 1;
  const int wn   = wave & 1;
  const int r0   = blockIdx.x * BM;

  for (int i = t; i < BM * (F_DIM / 4); i += GTHR) {
    int r  = i / 75;
    int c4 = i - r * 75;
    float4 v = *(const float4*)(inputs + (size_t)(r0 + r) * F_DIM + c4 * 4);
    ushort4 o;
    o.x = f2bf(v.x); o.y = f2bf(v.y); o.z = f2bf(v.z); o.w = f2bf(v.w);
    *(ushort4*)&A_lds[r * LDTA + c4 * 4] = o;
  }
  for (int i = t; i < BM * 7; i += GTHR) {
    int r = i / 7, p = i - r * 7;
    *(ushort4*)&A_lds[r * LDTA + 300 + p * 4] = (ushort4){0, 0, 0, 0};
  }

  const int brow = t >> 3, bkof = t & 7;
  short8 bv[2];
  auto LOADB = [&](int tile) {
    const int c0 = (tile / 5) * BN;
    const int k0 = (tile % 5) * BK;
#pragma unroll
    for (int j = 0; j < 2; ++j)
      bv[j] = *(const short8*)(Ybf + (size_t)(c0 + j * 64 + brow) * F_PAD + k0 + bkof * 8);
  };
  auto WRITEB = [&](int buf) {
#pragma unroll
    for (int j = 0; j < 2; ++j)
      *(short8*)&B_lds[buf][(j * 64 + brow) * LDTB + bkof * 8] = bv[j];
  };

  f32x4 acc[2][4];
#pragma unroll
  for (int mt = 0; mt < 2; ++mt)
#pragma unroll
    for (int nt = 0; nt < 4; ++nt) acc[mt][nt] = (f32x4){0.f, 0.f, 0.f, 0.f};

  LOADB(0);
  __syncthreads();
  WRITEB(0);
  __syncthreads();

  const int NT = 8 * 5;
#pragma unroll 1
  for (int tile = 0; tile < NT; ++tile) {
    const int kt = tile % 5;
    if (tile < NT - 1) LOADB(tile + 1);

    // ---- fused keygen: 2 row-pairs x 2 col-halves per tile, tiles 0..31 ----
    if (FUSED && tile < 32) {
#pragma unroll
      for (int mm = 0; mm < 2; ++mm) {
        const int m = 2 * tile + mm;                       // rp_loc 0..63
        const size_t rpg = (size_t)(r0 >> 1) + m;
        const int rA = r0 + 2 * m;
        const TFSched sA = tf_make(subk[2 * rA],     subk[2 * rA + 1]);
        const TFSched sB = tf_make(subk[2 * rA + 2], subk[2 * rA + 3]);
#pragma unroll
        for (int half = 0; half < 2; ++half) {
          const uint32_t c = (uint32_t)(t + 512 * half);   // col 0..1023
          uint32_t kA = tf_hash(sA, c);
          uint32_t kB = tf_hash(sB, c);
          keyP[rpg * D_PAD + c] = (kA >> 16) | (kB & 0xFFFF0000u);
        }
      }
    }

    const uint16_t* Bc = B_lds[tile & 1];
#pragma unroll
    for (int ks = 0; ks < 2; ++ks) {
      short8 a[2], b[4];
#pragma unroll
      for (int mt = 0; mt < 2; ++mt)
        a[mt] = *(const short8*)&A_lds[(wm * 32 + mt * 16 + l15) * LDTA + kt * BK + ks * 32 + g * 8];
#pragma unroll
      for (int nt = 0; nt < 4; ++nt)
        b[nt] = *(const short8*)&Bc[(wn * 64 + nt * 16 + l15) * LDTB + ks * 32 + g * 8];
#pragma unroll
      for (int mt = 0; mt < 2; ++mt)
#pragma unroll
        for (int nt = 0; nt < 4; ++nt)
          acc[mt][nt] = __builtin_amdgcn_mfma_f32_16x16x32_bf16(a[mt], b[nt], acc[mt][nt], 0, 0, 0);
    }
    if (kt == 4) {
      const int c0 = (tile / 5) * BN;
#pragma unroll
      for (int mt = 0; mt < 2; ++mt)
#pragma unroll
        for (int nt = 0; nt < 4; ++nt) {
          const int col = c0 + wn * 64 + nt * 16 + l15;
#pragma unroll
          for (int p = 0; p < 2; ++p) {
            uint32_t lo = f2bf(acc[mt][nt][2 * p]);
            uint32_t hi = f2bf(acc[mt][nt][2 * p + 1]);
            size_t rp = (size_t)(r0 >> 1) + wm * 16 + mt * 8 + g * 2 + p;
            Spair[rp * D_PAD + col] = (hi << 16) | lo;
          }
          acc[mt][nt] = (f32x4){0.f, 0.f, 0.f, 0.f};
        }
    }
    if (tile < NT - 1) {
      WRITEB((tile + 1) & 1);
      __syncthreads();
    }
  }

  // ---- fused loss phase: hash-free, reads block's own L2-hot Spair/keyP ----
  if (FUSED) {
    __syncthreads();   // drains vmcnt -> all block stores visible via L2
#pragma unroll 1
    for (int j = 0; j < 8; ++j) {
      const int rp_loc = wave * 8 + j;
      const size_t rpg = (size_t)(r0 >> 1) + rp_loc;
      const int rA = r0 + 2 * rp_loc;
      const int yA = yidx[rA], yB = yidx[rA + 1];
      const uint32_t* Sp = Spair + rpg * D_PAD;
      const uint32_t* Kp = keyP  + rpg * D_PAD;
      const float apA = bf2f_lo(Sp[yA]);
      const float apB = bf2f_hi(Sp[yB]);

      uint32_t an[16], kk[16];
#pragma unroll
      for (int q4 = 0; q4 < 4; ++q4) {
        uint4 v = *(const uint4*)(Sp + q4 * 256 + lane * 4);
        an[4 * q4 + 0] = v.x; an[4 * q4 + 1] = v.y;
        an[4 * q4 + 2] = v.z; an[4 * q4 + 3] = v.w;
        uint4 w = *(const uint4*)(Kp + q4 * 256 + lane * 4);
        kk[4 * q4 + 0] = w.x; kk[4 * q4 + 1] = w.y;
        kk[4 * q4 + 2] = w.z; kk[4 * q4 + 3] = w.w;
      }

      uint32_t mnA = 0xFFFFu, mnB = 0xFFFFu;
#pragma unroll
      for (int q = 0; q < 16; ++q) {
        const int c = (q >> 2) * 256 + lane * 4 + (q & 3);
        const uint32_t kA = kk[q] & 0xFFFFu, kB = kk[q] >> 16;
        const float anA = bf2f_lo(an[q]), anB = bf2f_hi(an[q]);
        if ((c < D_CLS) && (c != yA) && (apA - anA) > MARGIN) mnA = (kA < mnA) ? kA : mnA;
        if ((c < D_CLS) && (c != yB) && (apB - anB) > MARGIN) mnB = (kB < mnB) ? kB : mnB;
      }
#pragma unroll
      for (int off = 1; off < 64; off <<= 1) {
        uint32_t oA = __shfl_xor(mnA, off, 64);
        uint32_t oB = __shfl_xor(mnB, off, 64);
        mnA = (oA < mnA) ? oA : mnA;
        mnB = (oB < mnB) ? oB : mnB;
      }

      float smA = 0.f, smB = 0.f; int ctA = 0, ctB = 0;
#pragma unroll
      for (int q = 0; q < 16; ++q) {
        const int c = (q >> 2) * 256 + lane * 4 + (q & 3);
        const uint32_t kA = kk[q] & 0xFFFFu, kB = kk[q] >> 16;
        const float anA = bf2f_lo(an[q]), anB = bf2f_hi(an[q]);
        if ((c < D_CLS) && (c != yA) && kA < mnA) { smA += MARGIN + anA - apA; ctA += 1; }
        if ((c < D_CLS) && (c != yB) && kB < mnB) { smB += MARGIN + anB - apB; ctB += 1; }
      }
#pragma unroll
      for (int off = 1; off < 64; off <<= 1) {
        smA += __shfl_xor(smA, off, 64);
        smB += __shfl_xor(smB, off, 64);
        ctA += __shfl_xor(ctA, off, 64);
        ctB += __shfl_xor(ctB, off, 64);
      }
      if (lane == 0) {
        rowSum[rA]     = smA;  rowCnt[rA]     = ctA + (mnA != 0xFFFFu ? 1 : 0);
        rowSum[rA + 1] = smB;  rowCnt[rA + 1] = ctB + (mnB != 0xFFFFu ? 1 : 0);
      }
    }
  }
}

// ============ K2 (mid-tier fallback): hash + loss; one wave per row-pair ======
__launch_bounds__(256, 2)
__global__ void hash_loss(const uint32_t* __restrict__ Spair,
                          const uint32_t* __restrict__ subk,
                          const int* __restrict__ yidx,
                          float* __restrict__ rowSum,
                          int* __restrict__ rowCnt) {
  const int lane = threadIdx.x & 63;
  const int wave = threadIdx.x >> 6;
  const int rp   = blockIdx.x * 4 + wave;
  const int rA   = 2 * rp;
  const int rB   = 2 * rp + 1;

  const int yA = yidx[rA], yB = yidx[rB];
  const TFSched sA = tf_make(subk[2 * rA], subk[2 * rA + 1]);
  const TFSched sB = tf_make(subk[2 * rB], subk[2 * rB + 1]);

  const uint32_t* Sp = Spair + (size_t)rp * D_PAD;
  const float apA = bf2f_lo(Sp[yA]);
  const float apB = bf2f_hi(Sp[yB]);

  uint32_t an[16];
#pragma unroll
  for (int j = 0; j < 4; ++j) {
    uint4 v = *(const uint4*)(Sp + j * 256 + lane * 4);
    an[4 * j + 0] = v.x; an[4 * j + 1] = v.y;
    an[4 * j + 2] = v.z; an[4 * j + 3] = v.w;
  }

  uint32_t skAB[16];
  uint32_t pkA = 0xFFFFFFFFu, pkB = 0xFFFFFFFFu;
#pragma unroll
  for (int q = 0; q < 16; ++q) {
    const int c = (q >> 2) * 256 + lane * 4 + (q & 3);
    uint32_t kA = tf_hash(sA, (uint32_t)c);
    uint32_t kB = tf_hash(sB, (uint32_t)c);
    skAB[q] = (kA >> 16) | (kB & 0xFFFF0000u);
    float anA = bf2f_lo(an[q]);
    float anB = bf2f_hi(an[q]);
    if ((c < D_CLS) && (c != yA) && (apA - anA) > MARGIN) {
      pkA = (kA < pkA) ? kA : pkA;
    }
    if ((c < D_CLS) && (c != yB) && (apB - anB) > MARGIN) {
      pkB = (kB < pkB) ? kB : pkB;
    }
  }
#pragma unroll
  for (int off = 1; off < 64; off <<= 1) {
    uint32_t oA = __shfl_xor(pkA, off, 64);
    uint32_t oB = __shfl_xor(pkB, off, 64);
    pkA = (oA < pkA) ? oA : pkA;
    pkB = (oB < pkB) ? oB : pkB;
  }
  const uint32_t pA16 = pkA >> 16;
  const uint32_t pB16 = pkB >> 16;

  float smA = 0.f, smB = 0.f; int ctA = 0, ctB = 0;
#pragma unroll
  for (int q = 0; q < 16; ++q) {
    const int c = (q >> 2) * 256 + lane * 4 + (q & 3);
    float anA = bf2f_lo(an[q]);
    float anB = bf2f_hi(an[q]);
    if ((c < D_CLS) && (c != yA) && (skAB[q] & 0xFFFFu) < pA16) {
      smA += MARGIN + anA - apA; ctA += 1;
    }
    if ((c < D_CLS) && (c != yB) && (skAB[q] >> 16) < pB16) {
      smB += MARGIN + anB - apB; ctB += 1;
    }
  }
#pragma unroll
  for (int off = 1; off < 64; off <<= 1) {
    smA += __shfl_xor(smA, off, 64);
    smB += __shfl_xor(smB, off, 64);
    ctA += __shfl_xor(ctA, off, 64);
    ctB += __shfl_xor(ctB, off, 64);
  }
  if (lane == 0) {
    rowSum[rA] = smA;
    rowCnt[rA] = ctA + (pkA != 0xFFFFFFFFu ? 1 : 0);
    rowSum[rB] = smB;
    rowCnt[rB] = ctB + (pkB != 0xFFFFFFFFu ? 1 : 0);
  }
}

// ============ fused fallback (round-13-verified) ============
__launch_bounds__(NTHR, 4)
__global__ void triplet_fused(const float* __restrict__ inputs,
                              const uint16_t* __restrict__ Ybf,
                              const int* __restrict__ yidx,
                              float* __restrict__ rowSum,
                              int* __restrict__ rowCnt) {
  __shared__ __align__(16) uint16_t SH[D_PAD * SROW];
  __shared__ int      y_sh[M_PB];
  __shared__ uint32_t subk_sh[M_PB][2];

  const int t    = threadIdx.x;
  const int wave = t >> 6;
  const int lane = t & 63;
  const int l15  = lane & 15;
  const int g    = lane >> 4;
  const int row0 = blockIdx.x * M_PB;
  const int colbase = wave * (NT_PW * 16);

  if (t < M_PB) {
    y_sh[t] = yidx[row0 + t];
    uint32_t r1, r2, s1, s2;
    threefry2x32(0u, 42u, 0u, (uint32_t)(row0 + t), r1, r2);
    threefry2x32(r1, r2, 0u, 1u, s1, s2);
    subk_sh[t][0] = s1; subk_sh[t][1] = s2;
  }

  uint16_t* A_fl = SH;
  for (int i = t; i < M_PB * (F_DIM / 4); i += NTHR) {
    int r  = i / 75;
    int c4 = i - r * 75;
    float4 v = *(const float4*)(inputs + (size_t)(row0 + r) * F_DIM + c4 * 4);
    ushort4 o;
    o.x = f2bf(v.x); o.y = f2bf(v.y); o.z = f2bf(v.z); o.w = f2bf(v.w);
    *(ushort4*)&A_fl[r * LDA + c4 * 4] = o;
  }
  for (int i = t; i < M_PB * 5; i += NTHR) {
    int r = i / 5, p = i - r * 5;
    *(ushort4*)&A_fl[r * LDA + 300 + p * 4] = (ushort4){0, 0, 0, 0};
  }
  __syncthreads();

  f32x4 acc[MT_PB][NT_PW];
#pragma unroll
  for (int mt = 0; mt < MT_PB; ++mt)
#pragma unroll
    for (int nt = 0; nt < NT_PW; ++nt) acc[mt][nt] = (f32x4){0.f, 0.f, 0.f, 0.f};

  const uint16_t* gB[NT_PW];
#pragma unroll
  for (int nt = 0; nt < NT_PW; ++nt) {
    int j = colbase + nt * 16 + l15;
    gB[nt] = Ybf + (size_t)j * F_PAD + (g << 3);
  }
  const uint16_t* aBase = &A_fl[l15 * LDA + (g << 3)];

#pragma unroll 2
  for (int ks = 0; ks < F_PAD / 32; ++ks) {
    short8 b[NT_PW], a[MT_PB];
#pragma unroll
    for (int nt = 0; nt < NT_PW; ++nt)
      b[nt] = *(const short8*)(gB[nt] + ks * 32);
#pragma unroll
    for (int mt = 0; mt < MT_PB; ++mt)
      a[mt] = *(const short8*)(aBase + mt * 16 * LDA + ks * 32);
#pragma unroll
    for (int mt = 0; mt < MT_PB; ++mt)
#pragma unroll
      for (int nt = 0; nt < NT_PW; ++nt)
        acc[mt][nt] = __builtin_amdgcn_mfma_f32_16x16x32_bf16(a[mt], b[nt], acc[mt][nt], 0, 0, 0);
  }

  __syncthreads();

#pragma unroll
  for (int mt = 0; mt < MT_PB; ++mt)
#pragma unroll
    for (int nt = 0; nt < NT_PW; ++nt) {
      int col = colbase + nt * 16 + l15;
#pragma unroll
      for (int p = 0; p < 2; ++p) {
        uint32_t lo = f2bf(acc[mt][nt][2 * p]);
        uint32_t hi = f2bf(acc[mt][nt][2 * p + 1]);
        *(uint32_t*)&SH[col * SROW + mt * 16 + (g << 2) + 2 * p] = (hi << 16) | lo;
      }
    }
  __syncthreads();

#pragma unroll
  for (int pr = 0; pr < 2; ++pr) {
    const int rA = wave * 4 + pr * 2;
    const int rB = rA + 1;
    const int yA = y_sh[rA], yB = y_sh[rB];
    const uint32_t a1 = subk_sh[rA][0], a2 = subk_sh[rA][1];
    const uint32_t b1 = subk_sh[rB][0], b2 = subk_sh[rB][1];
    const float apA = bf2f(SH[yA * SROW + rA]);
    const float apB = bf2f(SH[yB * SROW + rB]);

    uint32_t skA[16], skB[16];
    uint32_t pkA = 0xFFFFFFFFu, pkB = 0xFFFFFFFFu;
#pragma unroll
    for (int q = 0; q < 16; ++q) {
      const int c = q * 64 + lane;
      uint32_t xA, yAo, xB, yBo;
      threefry2x32(a1, a2, 0u, (uint32_t)c, xA, yAo);
      threefry2x32(b1, b2, 0u, (uint32_t)c, xB, yBo);
      skA[q] = xA ^ yAo;
      skB[q] = xB ^ yBo;
      float anA = bf2f(SH[c * SROW + rA]);
      float anB = bf2f(SH[c * SROW + rB]);
      if ((c < D_CLS) && (c != yA) && (apA - anA) > MARGIN) {
        pkA = (skA[q] < pkA) ? skA[q] : pkA;
      }
      if ((c < D_CLS) && (c != yB) && (apB - anB) > MARGIN) {
        pkB = (skB[q] < pkB) ? skB[q] : pkB;
      }
    }
#pragma unroll
    for (int off = 1; off < 64; off <<= 1) {
      uint32_t oA = __shfl_xor(pkA, off, 64);
      uint32_t oB = __shfl_xor(pkB, off, 64);
      pkA = (oA < pkA) ? oA : pkA;
      pkB = (oB < pkB) ? oB : pkB;
    }
    float smA = 0.f, smB = 0.f; int ctA = 0, ctB = 0;
#pragma unroll
    for (int q = 0; q < 16; ++q) {
      const int c = q * 64 + lane;
      float anA = bf2f(SH[c * SROW + rA]);
      float anB = bf2f(SH[c * SROW + rB]);
      if ((c < D_CLS) && (c != yA) && skA[q] < pkA) { smA += MARGIN + anA - apA; ctA += 1; }
      if ((c < D_CLS) && (c != yB) && skB[q] < pkB) { smB += MARGIN + anB - apB; ctB += 1; }
    }
#pragma unroll
    for (int off = 1; off < 64; off <<= 1) {
      smA += __shfl_xor(smA, off, 64);
      smB += __shfl_xor(smB, off, 64);
      ctA += __shfl_xor(ctA, off, 64);
      ctB += __shfl_xor(ctB, off, 64);
    }
    if (lane == 0) {
      rowSum[row0 + rA] = smA;
      rowCnt[row0 + rA] = ctA + (pkA != 0xFFFFFFFFu ? 1 : 0);
      rowSum[row0 + rB] = smB;
      rowCnt[row0 + rB] = ctB + (pkB != 0xFFFFFFFFu ? 1 : 0);
    }
  }
}

// ============ two-stage reduction ============
__global__ void reduce_part(const float* __restrict__ rowSum,
                            const int* __restrict__ rowCnt,
                            float* __restrict__ pS, int* __restrict__ pC) {
  __shared__ float ss[4];
  __shared__ int   sc[4];
  const int base = blockIdx.x * (N_ROWS / NPART);
  float s = 0.f; int c = 0;
  for (int i = threadIdx.x; i < N_ROWS / NPART; i += 256) {
    s += rowSum[base + i];
    c += rowCnt[base + i];
  }
#pragma unroll
  for (int off = 32; off > 0; off >>= 1) {
    s += __shfl_down(s, (unsigned)off, 64);
    c += __shfl_down(c, (unsigned)off, 64);
  }
  int wid = threadIdx.x >> 6, lane = threadIdx.x & 63;
  if (lane == 0) { ss[wid] = s; sc[wid] = c; }
  __syncthreads();
  if (threadIdx.x == 0) {
    pS[blockIdx.x] = ss[0] + ss[1] + ss[2] + ss[3];
    pC[blockIdx.x] = sc[0] + sc[1] + sc[2] + sc[3];
  }
}

__global__ void reduce_final(const float* __restrict__ pS,
                             const int* __restrict__ pC,
                             float* __restrict__ out) {
  const int lane = threadIdx.x;
  float s = (lane < NPART) ? pS[lane] : 0.f;
  int   c = (lane < NPART) ? pC[lane] : 0;
#pragma unroll
  for (int off = 32; off > 0; off >>= 1) {
    s += __shfl_down(s, (unsigned)off, 64);
    c += __shfl_down(c, (unsigned)off, 64);
  }
  if (lane == 0) out[0] = s / (float)(c < 1 ? 1 : c);
}

extern "C" void kernel_launch(void* const* d_in, const int* in_sizes, int n_in,
                              void* d_out, int out_size, void* d_ws, size_t ws_size,
                              hipStream_t stream) {
  const float* inputs = (const float*)d_in[0];
  const float* Y      = (const float*)d_in[1];
  const int*   yidx   = (const int*)d_in[2];
  float* out = (float*)d_out;

  char* ws = (char*)d_ws;
  size_t off = 0;
  uint16_t* Ybf    = (uint16_t*)(ws + off); off += (size_t)D_PAD * F_PAD * 2;
  float*    rowSum = (float*)(ws + off);    off += (size_t)N_ROWS * 4;
  int*      rowCnt = (int*)(ws + off);      off += (size_t)N_ROWS * 4;
  uint32_t* subk   = (uint32_t*)(ws + off); off += (size_t)N_ROWS * 8;
  float*    pS     = (float*)(ws + off);    off += (size_t)NPART * 4;
  int*      pC     = (int*)(ws + off);      off += (size_t)NPART * 4;
  off = (off + 255) & ~(size_t)255;
  uint32_t* Spair  = (uint32_t*)(ws + off); off += (size_t)(N_ROWS / 2) * D_PAD * 4;
  const size_t need_mid = off;
  off = (off + 255) & ~(size_t)255;
  uint32_t* keyP   = (uint32_t*)(ws + off); off += (size_t)(N_ROWS / 2) * D_PAD * 4;
  const size_t need_full = off;

  hipLaunchKernelGGL(prep, dim3((D_PAD * F_PAD + 255) / 256), dim3(256),
                     0, stream, Y, Ybf, subk);
  if (ws_size >= need_full) {
    gemm_core<1><<<dim3(N_ROWS / BM), dim3(GTHR), 0, stream>>>(
        inputs, Ybf, Spair, keyP, subk, yidx, rowSum, rowCnt);
  } else if (ws_size >= need_mid) {
    gemm_core<0><<<dim3(N_ROWS / BM), dim3(GTHR), 0, stream>>>(
        inputs, Ybf, Spair, (uint32_t*)nullptr, subk, yidx, rowSum, rowCnt);
    hipLaunchKernelGGL(hash_loss, dim3(N_ROWS / 8), dim3(256),
                       0, stream, Spair, subk, yidx, rowSum, rowCnt);
  } else {
    hipLaunchKernelGGL(triplet_fused, dim3(N_ROWS / M_PB), dim3(NTHR),
                       0, stream, inputs, Ybf, yidx, rowSum, rowCnt);
  }
  hipLaunchKernelGGL(reduce_part, dim3(NPART), dim3(256), 0, stream,
                     rowSum, rowCnt, pS, pC);
  hipLaunchKernelGGL(reduce_final, dim3(1), dim3(64), 0, stream, pS, pC, out);
}

// Round 2
// 129.527 us; speedup vs baseline: 1.0657x; 1.0657x over previous
//
#include <hip/hip_runtime.h>
#include <stdint.h>

#define N_ROWS 32768
#define D_CLS  1000
#define D_PAD  1024
#define F_DIM  300
#define F_PAD  320
#define MARGIN 0.1f

// ---- persistent-A GEMM params ----
#define BM     128
#define BN     128
#define BK     64
#define GTHR   512           // GEMM waves: 8 waves = 4 M-groups x 2 N-groups
#define KGTHR  1024          // gemm_kg total: 8 GEMM waves + 8 keygen waves
#define LDTA   328           // A LDS row stride (300 + 28 pad, 16B aligned)
#define LDTB   72            // B LDS row stride (64 + 8 pad)

// ---- fused fallback params ----
#define M_PB   32
#define NTHR   512
#define NT_PW  8
#define MT_PB  2
#define LDA    328
#define SROW   34

#define NPART  32            // reduce stage-1 blocks

typedef short short8 __attribute__((ext_vector_type(8)));
typedef float f32x4  __attribute__((ext_vector_type(4)));

__device__ __forceinline__ uint32_t rotl32(uint32_t x, int r) {
  return (x << r) | (x >> (32 - r));
}

// JAX threefry2x32 (20 rounds) — bit-exact
__device__ __forceinline__ void threefry2x32(uint32_t k0, uint32_t k1,
                                             uint32_t x0, uint32_t x1,
                                             uint32_t& o0, uint32_t& o1) {
  uint32_t k2 = k0 ^ k1 ^ 0x1BD11BDAu;
  x0 += k0; x1 += k1;
#define TF_R(r) { x0 += x1; x1 = rotl32(x1, (r)); x1 ^= x0; }
  TF_R(13) TF_R(15) TF_R(26) TF_R(6)
  x0 += k1; x1 += k2 + 1u;
  TF_R(17) TF_R(29) TF_R(16) TF_R(24)
  x0 += k2; x1 += k0 + 2u;
  TF_R(13) TF_R(15) TF_R(26) TF_R(6)
  x0 += k0; x1 += k1 + 3u;
  TF_R(17) TF_R(29) TF_R(16) TF_R(24)
  x0 += k1; x1 += k2 + 4u;
  TF_R(13) TF_R(15) TF_R(26) TF_R(6)
  x0 += k2; x1 += k0 + 5u;
#undef TF_R
  o0 = x0; o1 = x1;
}

// Hoisted-schedule threefry (r17-verified): same bits, rotates via v_alignbit.
struct TFSched {
  uint32_t k0, k1, k2, k2p1, k0p2, k1p3, k2p4, k0p5;
};
__device__ __forceinline__ TFSched tf_make(uint32_t k0, uint32_t k1) {
  TFSched s;
  s.k0 = k0; s.k1 = k1;
  s.k2 = k0 ^ k1 ^ 0x1BD11BDAu;
  s.k2p1 = s.k2 + 1u; s.k0p2 = k0 + 2u; s.k1p3 = k1 + 3u;
  s.k2p4 = s.k2 + 4u; s.k0p5 = k0 + 5u;
  return s;
}
__device__ __forceinline__ uint32_t tf_hash(const TFSched& s, uint32_t c) {
  uint32_t x0 = s.k0, x1 = c + s.k1;
#define TFH(r) { x0 += x1; x1 = __builtin_amdgcn_alignbit(x1, x1, 32 - (r)); x1 ^= x0; }
  TFH(13) TFH(15) TFH(26) TFH(6)
  x0 += s.k1; x1 += s.k2p1;
  TFH(17) TFH(29) TFH(16) TFH(24)
  x0 += s.k2; x1 += s.k0p2;
  TFH(13) TFH(15) TFH(26) TFH(6)
  x0 += s.k0; x1 += s.k1p3;
  TFH(17) TFH(29) TFH(16) TFH(24)
  x0 += s.k1; x1 += s.k2p4;
  TFH(13) TFH(15) TFH(26) TFH(6)
  x0 += s.k2; x1 += s.k0p5;
#undef TFH
  return x0 ^ x1;
}

__device__ __forceinline__ uint16_t f2bf(float f) {   // RNE fp32 -> bf16
  uint32_t u = __builtin_bit_cast(uint32_t, f);
  return (uint16_t)((u + 0x7FFFu + ((u >> 16) & 1u)) >> 16);
}
__device__ __forceinline__ float bf2f(uint16_t v) {
  return __builtin_bit_cast(float, (uint32_t)v << 16);
}
__device__ __forceinline__ float bf2f_lo(uint32_t v) {
  return __builtin_bit_cast(float, v << 16);
}
__device__ __forceinline__ float bf2f_hi(uint32_t v) {
  return __builtin_bit_cast(float, v & 0xFFFF0000u);
}

// prep: Y fp32 -> Ybf bf16 (zero-padded) AND per-row subkeys
__global__ void prep(const float* __restrict__ Y, uint16_t* __restrict__ Ybf,
                     uint32_t* __restrict__ subk) {
  int i = blockIdx.x * 256 + threadIdx.x;
  if (i < D_PAD * F_PAD) {
    int j = i / F_PAD;
    int k = i - j * F_PAD;
    float v = (j < D_CLS && k < F_DIM) ? Y[j * F_DIM + k] : 0.f;
    Ybf[i] = f2bf(v);
  }
  if (i < N_ROWS) {
    uint32_t r1, r2, s1, s2;
    threefry2x32(0u, 42u, 0u, (uint32_t)i, r1, r2);
    threefry2x32(r1, r2, 0u, 1u, s1, s2);
    subk[2 * i]     = s1;
    subk[2 * i + 1] = s2;
  }
}

// ====== K1: wave-specialized GEMM + keygen ======
// 16 waves/block: waves 0-7 run the proven MFMA GEMM (2/SIMD, unchanged
// schedule); waves 8-15 are pure threefry keygen waves (2/SIMD) that saturate
// VALU issue while GEMM waves idle at barriers (m114: MFMA/VALU co-schedule).
// Barriers are OUTSIDE the role branch -> all 16 waves execute the identical
// 41-barrier sequence.  Keygen: per tile 0..31, each keygen wave handles one
// row-pair x 256 cols; lane hashes cols 4*lane..4*lane+3 for rows A,B and
// stores one packed uint4 (lo16=top16(keyA), hi16=top16(keyB)).
__launch_bounds__(KGTHR, 4)
__global__ void gemm_kg(const float* __restrict__ inputs,
                        const uint16_t* __restrict__ Ybf,
                        uint32_t* __restrict__ Spair,
                        uint32_t* __restrict__ keyP,
                        const uint32_t* __restrict__ subk) {
  __shared__ __align__(16) uint16_t A_lds[BM * LDTA];     // 83,968 B
  __shared__ __align__(16) uint16_t B_lds[2][BN * LDTB];  // 36,864 B

  const int t    = threadIdx.x;
  const int wave = t >> 6;
  const int lane = t & 63;
  const int l15  = lane & 15;
  const int g    = lane >> 4;
  const bool isg = wave < 8;          // GEMM role
  const int wm   = wave >> 1;         // valid for GEMM waves
  const int wn   = wave & 1;
  const int kw   = wave - 8;          // valid for keygen waves
  const int r0   = blockIdx.x * BM;

  // A staging: all 1024 threads cooperate
  for (int i = t; i < BM * (F_DIM / 4); i += KGTHR) {
    int r  = i / 75;
    int c4 = i - r * 75;
    float4 v = *(const float4*)(inputs + (size_t)(r0 + r) * F_DIM + c4 * 4);
    ushort4 o;
    o.x = f2bf(v.x); o.y = f2bf(v.y); o.z = f2bf(v.z); o.w = f2bf(v.w);
    *(ushort4*)&A_lds[r * LDTA + c4 * 4] = o;
  }
  for (int i = t; i < BM * 7; i += KGTHR) {
    int r = i / 7, p = i - r * 7;
    *(ushort4*)&A_lds[r * LDTA + 300 + p * 4] = (ushort4){0, 0, 0, 0};
  }

  const int brow = t >> 3, bkof = t & 7;   // only meaningful for t < 512
  short8 bv[2];
  auto LOADB = [&](int tile) {
    const int c0 = (tile / 5) * BN;
    const int k0 = (tile % 5) * BK;
#pragma unroll
    for (int j = 0; j < 2; ++j)
      bv[j] = *(const short8*)(Ybf + (size_t)(c0 + j * 64 + brow) * F_PAD + k0 + bkof * 8);
  };
  auto WRITEB = [&](int buf) {
#pragma unroll
    for (int j = 0; j < 2; ++j)
      *(short8*)&B_lds[buf][(j * 64 + brow) * LDTB + bkof * 8] = bv[j];
  };

  f32x4 acc[2][4];
#pragma unroll
  for (int mt = 0; mt < 2; ++mt)
#pragma unroll
    for (int nt = 0; nt < 4; ++nt) acc[mt][nt] = (f32x4){0.f, 0.f, 0.f, 0.f};

  if (isg) LOADB(0);
  __syncthreads();
  if (isg) WRITEB(0);
  __syncthreads();

  const int NT = 8 * 5;
#pragma unroll 1
  for (int tile = 0; tile < NT; ++tile) {
    if (isg) {
      // ---------------- GEMM role (identical to proven gemm_s) ----------------
      const int kt = tile % 5;
      if (tile < NT - 1) LOADB(tile + 1);
      const uint16_t* Bc = B_lds[tile & 1];
#pragma unroll
      for (int ks = 0; ks < 2; ++ks) {
        short8 a[2], b[4];
#pragma unroll
        for (int mt = 0; mt < 2; ++mt)
          a[mt] = *(const short8*)&A_lds[(wm * 32 + mt * 16 + l15) * LDTA + kt * BK + ks * 32 + g * 8];
#pragma unroll
        for (int nt = 0; nt < 4; ++nt)
          b[nt] = *(const short8*)&Bc[(wn * 64 + nt * 16 + l15) * LDTB + ks * 32 + g * 8];
#pragma unroll
        for (int mt = 0; mt < 2; ++mt)
#pragma unroll
          for (int nt = 0; nt < 4; ++nt)
            acc[mt][nt] = __builtin_amdgcn_mfma_f32_16x16x32_bf16(a[mt], b[nt], acc[mt][nt], 0, 0, 0);
      }
      if (kt == 4) {
        const int c0 = (tile / 5) * BN;
#pragma unroll
        for (int mt = 0; mt < 2; ++mt)
#pragma unroll
          for (int nt = 0; nt < 4; ++nt) {
            const int col = c0 + wn * 64 + nt * 16 + l15;
#pragma unroll
            for (int p = 0; p < 2; ++p) {
              uint32_t lo = f2bf(acc[mt][nt][2 * p]);
              uint32_t hi = f2bf(acc[mt][nt][2 * p + 1]);
              size_t rp = (size_t)(r0 >> 1) + wm * 16 + mt * 8 + g * 2 + p;
              Spair[rp * D_PAD + col] = (hi << 16) | lo;
            }
            acc[mt][nt] = (f32x4){0.f, 0.f, 0.f, 0.f};
          }
      }
      if (tile < NT - 1) WRITEB((tile + 1) & 1);
    } else if (tile < 32) {
      // ---------------- keygen role ----------------
      const int rp_loc = kw * 8 + (tile >> 2);            // 8 row-pairs per wave
      const size_t rpg = (size_t)(r0 >> 1) + rp_loc;
      const int rA = r0 + 2 * rp_loc;
      const uint4 sk4 = *(const uint4*)(subk + 2 * rA);   // 16B aligned (rA even)
      const TFSched sA = tf_make(sk4.x, sk4.y);
      const TFSched sB = tf_make(sk4.z, sk4.w);
      const uint32_t c0 = (uint32_t)((tile & 3) * 256 + 4 * lane);
      uint4 ov;
      uint32_t o[4];
#pragma unroll
      for (int j = 0; j < 4; ++j) {
        uint32_t kA = tf_hash(sA, c0 + (uint32_t)j);
        uint32_t kB = tf_hash(sB, c0 + (uint32_t)j);
        o[j] = (kA >> 16) | (kB & 0xFFFF0000u);
      }
      ov.x = o[0]; ov.y = o[1]; ov.z = o[2]; ov.w = o[3];
      *(uint4*)(keyP + (rpg << 10) + c0) = ov;
    }
    if (tile < NT - 1) __syncthreads();
  }
}

// ============ K2: hash-free loss (streaming, 16 waves/CU) ============
// Bit-exact vs verified round-0/1 semantics: min over 16-bit truncated keys
// == truncation of 32-bit min (monotone), strict top16 compare unchanged.
__launch_bounds__(256, 4)
__global__ void loss_light(const uint32_t* __restrict__ Spair,
                           const uint32_t* __restrict__ keyP,
                           const int* __restrict__ yidx,
                           float* __restrict__ rowSum,
                           int* __restrict__ rowCnt) {
  const int lane = threadIdx.x & 63;
  const int wave = threadIdx.x >> 6;
  const int rp   = blockIdx.x * 4 + wave;
  const int rA   = 2 * rp;
  const int rB   = rA + 1;
  const int yA = yidx[rA], yB = yidx[rB];
  const uint32_t* Sp = Spair + (size_t)rp * D_PAD;
  const uint32_t* Kp = keyP  + (size_t)rp * D_PAD;
  const float apA = bf2f_lo(Sp[yA]);
  const float apB = bf2f_hi(Sp[yB]);

  uint32_t an[16], kk[16];
#pragma unroll
  for (int q4 = 0; q4 < 4; ++q4) {
    uint4 v = *(const uint4*)(Sp + q4 * 256 + lane * 4);
    an[4 * q4 + 0] = v.x; an[4 * q4 + 1] = v.y;
    an[4 * q4 + 2] = v.z; an[4 * q4 + 3] = v.w;
    uint4 w = *(const uint4*)(Kp + q4 * 256 + lane * 4);
    kk[4 * q4 + 0] = w.x; kk[4 * q4 + 1] = w.y;
    kk[4 * q4 + 2] = w.z; kk[4 * q4 + 3] = w.w;
  }

  uint32_t mnA = 0xFFFFu, mnB = 0xFFFFu;
#pragma unroll
  for (int q = 0; q < 16; ++q) {
    const int c = (q >> 2) * 256 + lane * 4 + (q & 3);
    const uint32_t kA = kk[q] & 0xFFFFu, kB = kk[q] >> 16;
    const float anA = bf2f_lo(an[q]), anB = bf2f_hi(an[q]);
    if ((c < D_CLS) && (c != yA) && (apA - anA) > MARGIN) mnA = (kA < mnA) ? kA : mnA;
    if ((c < D_CLS) && (c != yB) && (apB - anB) > MARGIN) mnB = (kB < mnB) ? kB : mnB;
  }
#pragma unroll
  for (int off = 1; off < 64; off <<= 1) {
    uint32_t oA = __shfl_xor(mnA, off, 64);
    uint32_t oB = __shfl_xor(mnB, off, 64);
    mnA = (oA < mnA) ? oA : mnA;
    mnB = (oB < mnB) ? oB : mnB;
  }

  float smA = 0.f, smB = 0.f; int ctA = 0, ctB = 0;
#pragma unroll
  for (int q = 0; q < 16; ++q) {
    const int c = (q >> 2) * 256 + lane * 4 + (q & 3);
    const uint32_t kA = kk[q] & 0xFFFFu, kB = kk[q] >> 16;
    const float anA = bf2f_lo(an[q]), anB = bf2f_hi(an[q]);
    if ((c < D_CLS) && (c != yA) && kA < mnA) { smA += MARGIN + anA - apA; ctA += 1; }
    if ((c < D_CLS) && (c != yB) && kB < mnB) { smB += MARGIN + anB - apB; ctB += 1; }
  }
#pragma unroll
  for (int off = 1; off < 64; off <<= 1) {
    smA += __shfl_xor(smA, off, 64);
    smB += __shfl_xor(smB, off, 64);
    ctA += __shfl_xor(ctA, off, 64);
    ctB += __shfl_xor(ctB, off, 64);
  }
  if (lane == 0) {
    rowSum[rA] = smA;  rowCnt[rA] = ctA + (mnA != 0xFFFFu ? 1 : 0);
    rowSum[rB] = smB;  rowCnt[rB] = ctB + (mnB != 0xFFFFu ? 1 : 0);
  }
}

// ============ mid-tier fallback: plain GEMM (proven round-0) ============
__launch_bounds__(GTHR, 1)
__global__ void gemm_s(const float* __restrict__ inputs,
                       const uint16_t* __restrict__ Ybf,
                       uint32_t* __restrict__ Spair) {
  __shared__ __align__(16) uint16_t A_lds[BM * LDTA];
  __shared__ __align__(16) uint16_t B_lds[2][BN * LDTB];

  const int t    = threadIdx.x;
  const int wave = t >> 6;
  const int lane = t & 63;
  const int l15  = lane & 15;
  const int g    = lane >> 4;
  const int wm   = wave >> 1;
  const int wn   = wave & 1;
  const int r0   = blockIdx.x * BM;

  for (int i = t; i < BM * (F_DIM / 4); i += GTHR) {
    int r  = i / 75;
    int c4 = i - r * 75;
    float4 v = *(const float4*)(inputs + (size_t)(r0 + r) * F_DIM + c4 * 4);
    ushort4 o;
    o.x = f2bf(v.x); o.y = f2bf(v.y); o.z = f2bf(v.z); o.w = f2bf(v.w);
    *(ushort4*)&A_lds[r * LDTA + c4 * 4] = o;
  }
  for (int i = t; i < BM * 7; i += GTHR) {
    int r = i / 7, p = i - r * 7;
    *(ushort4*)&A_lds[r * LDTA + 300 + p * 4] = (ushort4){0, 0, 0, 0};
  }

  const int brow = t >> 3, bkof = t & 7;
  short8 bv[2];
  auto LOADB = [&](int tile) {
    const int c0 = (tile / 5) * BN;
    const int k0 = (tile % 5) * BK;
#pragma unroll
    for (int j = 0; j < 2; ++j)
      bv[j] = *(const short8*)(Ybf + (size_t)(c0 + j * 64 + brow) * F_PAD + k0 + bkof * 8);
  };
  auto WRITEB = [&](int buf) {
#pragma unroll
    for (int j = 0; j < 2; ++j)
      *(short8*)&B_lds[buf][(j * 64 + brow) * LDTB + bkof * 8] = bv[j];
  };

  f32x4 acc[2][4];
#pragma unroll
  for (int mt = 0; mt < 2; ++mt)
#pragma unroll
    for (int nt = 0; nt < 4; ++nt) acc[mt][nt] = (f32x4){0.f, 0.f, 0.f, 0.f};

  LOADB(0);
  __syncthreads();
  WRITEB(0);
  __syncthreads();

  const int NT = 8 * 5;
#pragma unroll 1
  for (int tile = 0; tile < NT; ++tile) {
    const int kt = tile % 5;
    if (tile < NT - 1) LOADB(tile + 1);
    const uint16_t* Bc = B_lds[tile & 1];
#pragma unroll
    for (int ks = 0; ks < 2; ++ks) {
      short8 a[2], b[4];
#pragma unroll
      for (int mt = 0; mt < 2; ++mt)
        a[mt] = *(const short8*)&A_lds[(wm * 32 + mt * 16 + l15) * LDTA + kt * BK + ks * 32 + g * 8];
#pragma unroll
      for (int nt = 0; nt < 4; ++nt)
        b[nt] = *(const short8*)&Bc[(wn * 64 + nt * 16 + l15) * LDTB + ks * 32 + g * 8];
#pragma unroll
      for (int mt = 0; mt < 2; ++mt)
#pragma unroll
        for (int nt = 0; nt < 4; ++nt)
          acc[mt][nt] = __builtin_amdgcn_mfma_f32_16x16x32_bf16(a[mt], b[nt], acc[mt][nt], 0, 0, 0);
    }
    if (kt == 4) {
      const int c0 = (tile / 5) * BN;
#pragma unroll
      for (int mt = 0; mt < 2; ++mt)
#pragma unroll
        for (int nt = 0; nt < 4; ++nt) {
          const int col = c0 + wn * 64 + nt * 16 + l15;
#pragma unroll
          for (int p = 0; p < 2; ++p) {
            uint32_t lo = f2bf(acc[mt][nt][2 * p]);
            uint32_t hi = f2bf(acc[mt][nt][2 * p + 1]);
            size_t rp = (size_t)(r0 >> 1) + wm * 16 + mt * 8 + g * 2 + p;
            Spair[rp * D_PAD + col] = (hi << 16) | lo;
          }
          acc[mt][nt] = (f32x4){0.f, 0.f, 0.f, 0.f};
        }
    }
    if (tile < NT - 1) {
      WRITEB((tile + 1) & 1);
      __syncthreads();
    }
  }
}

// ============ mid-tier fallback: hash + loss (proven) ============
__launch_bounds__(256, 2)
__global__ void hash_loss(const uint32_t* __restrict__ Spair,
                          const uint32_t* __restrict__ subk,
                          const int* __restrict__ yidx,
                          float* __restrict__ rowSum,
                          int* __restrict__ rowCnt) {
  const int lane = threadIdx.x & 63;
  const int wave = threadIdx.x >> 6;
  const int rp   = blockIdx.x * 4 + wave;
  const int rA   = 2 * rp;
  const int rB   = 2 * rp + 1;

  const int yA = yidx[rA], yB = yidx[rB];
  const TFSched sA = tf_make(subk[2 * rA], subk[2 * rA + 1]);
  const TFSched sB = tf_make(subk[2 * rB], subk[2 * rB + 1]);

  const uint32_t* Sp = Spair + (size_t)rp * D_PAD;
  const float apA = bf2f_lo(Sp[yA]);
  const float apB = bf2f_hi(Sp[yB]);

  uint32_t an[16];
#pragma unroll
  for (int j = 0; j < 4; ++j) {
    uint4 v = *(const uint4*)(Sp + j * 256 + lane * 4);
    an[4 * j + 0] = v.x; an[4 * j + 1] = v.y;
    an[4 * j + 2] = v.z; an[4 * j + 3] = v.w;
  }

  uint32_t skAB[16];
  uint32_t pkA = 0xFFFFFFFFu, pkB = 0xFFFFFFFFu;
#pragma unroll
  for (int q = 0; q < 16; ++q) {
    const int c = (q >> 2) * 256 + lane * 4 + (q & 3);
    uint32_t kA = tf_hash(sA, (uint32_t)c);
    uint32_t kB = tf_hash(sB, (uint32_t)c);
    skAB[q] = (kA >> 16) | (kB & 0xFFFF0000u);
    float anA = bf2f_lo(an[q]);
    float anB = bf2f_hi(an[q]);
    if ((c < D_CLS) && (c != yA) && (apA - anA) > MARGIN) {
      pkA = (kA < pkA) ? kA : pkA;
    }
    if ((c < D_CLS) && (c != yB) && (apB - anB) > MARGIN) {
      pkB = (kB < pkB) ? kB : pkB;
    }
  }
#pragma unroll
  for (int off = 1; off < 64; off <<= 1) {
    uint32_t oA = __shfl_xor(pkA, off, 64);
    uint32_t oB = __shfl_xor(pkB, off, 64);
    pkA = (oA < pkA) ? oA : pkA;
    pkB = (oB < pkB) ? oB : pkB;
  }
  const uint32_t pA16 = pkA >> 16;
  const uint32_t pB16 = pkB >> 16;

  float smA = 0.f, smB = 0.f; int ctA = 0, ctB = 0;
#pragma unroll
  for (int q = 0; q < 16; ++q) {
    const int c = (q >> 2) * 256 + lane * 4 + (q & 3);
    float anA = bf2f_lo(an[q]);
    float anB = bf2f_hi(an[q]);
    if ((c < D_CLS) && (c != yA) && (skAB[q] & 0xFFFFu) < pA16) {
      smA += MARGIN + anA - apA; ctA += 1;
    }
    if ((c < D_CLS) && (c != yB) && (skAB[q] >> 16) < pB16) {
      smB += MARGIN + anB - apB; ctB += 1;
    }
  }
#pragma unroll
  for (int off = 1; off < 64; off <<= 1) {
    smA += __shfl_xor(smA, off, 64);
    smB += __shfl_xor(smB, off, 64);
    ctA += __shfl_xor(ctA, off, 64);
    ctB += __shfl_xor(ctB, off, 64);
  }
  if (lane == 0) {
    rowSum[rA] = smA;
    rowCnt[rA] = ctA + (pkA != 0xFFFFFFFFu ? 1 : 0);
    rowSum[rB] = smB;
    rowCnt[rB] = ctB + (pkB != 0xFFFFFFFFu ? 1 : 0);
  }
}

// ============ fused fallback (round-13-verified) ============
__launch_bounds__(NTHR, 4)
__global__ void triplet_fused(const float* __restrict__ inputs,
                              const uint16_t* __restrict__ Ybf,
                              const int* __restrict__ yidx,
                              float* __restrict__ rowSum,
                              int* __restrict__ rowCnt) {
  __shared__ __align__(16) uint16_t SH[D_PAD * SROW];
  __shared__ int      y_sh[M_PB];
  __shared__ uint32_t subk_sh[M_PB][2];

  const int t    = threadIdx.x;
  const int wave = t >> 6;
  const int lane = t & 63;
  const int l15  = lane & 15;
  const int g    = lane >> 4;
  const int row0 = blockIdx.x * M_PB;
  const int colbase = wave * (NT_PW * 16);

  if (t < M_PB) {
    y_sh[t] = yidx[row0 + t];
    uint32_t r1, r2, s1, s2;
    threefry2x32(0u, 42u, 0u, (uint32_t)(row0 + t), r1, r2);
    threefry2x32(r1, r2, 0u, 1u, s1, s2);
    subk_sh[t][0] = s1; subk_sh[t][1] = s2;
  }

  uint16_t* A_fl = SH;
  for (int i = t; i < M_PB * (F_DIM / 4); i += NTHR) {
    int r  = i / 75;
    int c4 = i - r * 75;
    float4 v = *(const float4*)(inputs + (size_t)(row0 + r) * F_DIM + c4 * 4);
    ushort4 o;
    o.x = f2bf(v.x); o.y = f2bf(v.y); o.z = f2bf(v.z); o.w = f2bf(v.w);
    *(ushort4*)&A_fl[r * LDA + c4 * 4] = o;
  }
  for (int i = t; i < M_PB * 5; i += NTHR) {
    int r = i / 5, p = i - r * 5;
    *(ushort4*)&A_fl[r * LDA + 300 + p * 4] = (ushort4){0, 0, 0, 0};
  }
  __syncthreads();

  f32x4 acc[MT_PB][NT_PW];
#pragma unroll
  for (int mt = 0; mt < MT_PB; ++mt)
#pragma unroll
    for (int nt = 0; nt < NT_PW; ++nt) acc[mt][nt] = (f32x4){0.f, 0.f, 0.f, 0.f};

  const uint16_t* gB[NT_PW];
#pragma unroll
  for (int nt = 0; nt < NT_PW; ++nt) {
    int j = colbase + nt * 16 + l15;
    gB[nt] = Ybf + (size_t)j * F_PAD + (g << 3);
  }
  const uint16_t* aBase = &A_fl[l15 * LDA + (g << 3)];

#pragma unroll 2
  for (int ks = 0; ks < F_PAD / 32; ++ks) {
    short8 b[NT_PW], a[MT_PB];
#pragma unroll
    for (int nt = 0; nt < NT_PW; ++nt)
      b[nt] = *(const short8*)(gB[nt] + ks * 32);
#pragma unroll
    for (int mt = 0; mt < MT_PB; ++mt)
      a[mt] = *(const short8*)(aBase + mt * 16 * LDA + ks * 32);
#pragma unroll
    for (int mt = 0; mt < MT_PB; ++mt)
#pragma unroll
      for (int nt = 0; nt < NT_PW; ++nt)
        acc[mt][nt] = __builtin_amdgcn_mfma_f32_16x16x32_bf16(a[mt], b[nt], acc[mt][nt], 0, 0, 0);
  }

  __syncthreads();

#pragma unroll
  for (int mt = 0; mt < MT_PB; ++mt)
#pragma unroll
    for (int nt = 0; nt < NT_PW; ++nt) {
      int col = colbase + nt * 16 + l15;
#pragma unroll
      for (int p = 0; p < 2; ++p) {
        uint32_t lo = f2bf(acc[mt][nt][2 * p]);
        uint32_t hi = f2bf(acc[mt][nt][2 * p + 1]);
        *(uint32_t*)&SH[col * SROW + mt * 16 + (g << 2) + 2 * p] = (hi << 16) | lo;
      }
    }
  __syncthreads();

#pragma unroll
  for (int pr = 0; pr < 2; ++pr) {
    const int rA = wave * 4 + pr * 2;
    const int rB = rA + 1;
    const int yA = y_sh[rA], yB = y_sh[rB];
    const uint32_t a1 = subk_sh[rA][0], a2 = subk_sh[rA][1];
    const uint32_t b1 = subk_sh[rB][0], b2 = subk_sh[rB][1];
    const float apA = bf2f(SH[yA * SROW + rA]);
    const float apB = bf2f(SH[yB * SROW + rB]);

    uint32_t skA[16], skB[16];
    uint32_t pkA = 0xFFFFFFFFu, pkB = 0xFFFFFFFFu;
#pragma unroll
    for (int q = 0; q < 16; ++q) {
      const int c = q * 64 + lane;
      uint32_t xA, yAo, xB, yBo;
      threefry2x32(a1, a2, 0u, (uint32_t)c, xA, yAo);
      threefry2x32(b1, b2, 0u, (uint32_t)c, xB, yBo);
      skA[q] = xA ^ yAo;
      skB[q] = xB ^ yBo;
      float anA = bf2f(SH[c * SROW + rA]);
      float anB = bf2f(SH[c * SROW + rB]);
      if ((c < D_CLS) && (c != yA) && (apA - anA) > MARGIN) {
        pkA = (skA[q] < pkA) ? skA[q] : pkA;
      }
      if ((c < D_CLS) && (c != yB) && (apB - anB) > MARGIN) {
        pkB = (skB[q] < pkB) ? skB[q] : pkB;
      }
    }
#pragma unroll
    for (int off = 1; off < 64; off <<= 1) {
      uint32_t oA = __shfl_xor(pkA, off, 64);
      uint32_t oB = __shfl_xor(pkB, off, 64);
      pkA = (oA < pkA) ? oA : pkA;
      pkB = (oB < pkB) ? oB : pkB;
    }
    float smA = 0.f, smB = 0.f; int ctA = 0, ctB = 0;
#pragma unroll
    for (int q = 0; q < 16; ++q) {
      const int c = q * 64 + lane;
      float anA = bf2f(SH[c * SROW + rA]);
      float anB = bf2f(SH[c * SROW + rB]);
      if ((c < D_CLS) && (c != yA) && skA[q] < pkA) { smA += MARGIN + anA - apA; ctA += 1; }
      if ((c < D_CLS) && (c != yB) && skB[q] < pkB) { smB += MARGIN + anB - apB; ctB += 1; }
    }
#pragma unroll
    for (int off = 1; off < 64; off <<= 1) {
      smA += __shfl_xor(smA, off, 64);
      smB += __shfl_xor(smB, off, 64);
      ctA += __shfl_xor(ctA, off, 64);
      ctB += __shfl_xor(ctB, off, 64);
    }
    if (lane == 0) {
      rowSum[row0 + rA] = smA;
      rowCnt[row0 + rA] = ctA + (pkA != 0xFFFFFFFFu ? 1 : 0);
      rowSum[row0 + rB] = smB;
      rowCnt[row0 + rB] = ctB + (pkB != 0xFFFFFFFFu ? 1 : 0);
    }
  }
}

// ============ two-stage reduction ============
__global__ void reduce_part(const float* __restrict__ rowSum,
                            const int* __restrict__ rowCnt,
                            float* __restrict__ pS, int* __restrict__ pC) {
  __shared__ float ss[4];
  __shared__ int   sc[4];
  const int base = blockIdx.x * (N_ROWS / NPART);
  float s = 0.f; int c = 0;
  for (int i = threadIdx.x; i < N_ROWS / NPART; i += 256) {
    s += rowSum[base + i];
    c += rowCnt[base + i];
  }
#pragma unroll
  for (int off = 32; off > 0; off >>= 1) {
    s += __shfl_down(s, (unsigned)off, 64);
    c += __shfl_down(c, (unsigned)off, 64);
  }
  int wid = threadIdx.x >> 6, lane = threadIdx.x & 63;
  if (lane == 0) { ss[wid] = s; sc[wid] = c; }
  __syncthreads();
  if (threadIdx.x == 0) {
    pS[blockIdx.x] = ss[0] + ss[1] + ss[2] + ss[3];
    pC[blockIdx.x] = sc[0] + sc[1] + sc[2] + sc[3];
  }
}

__global__ void reduce_final(const float* __restrict__ pS,
                             const int* __restrict__ pC,
                             float* __restrict__ out) {
  const int lane = threadIdx.x;
  float s = (lane < NPART) ? pS[lane] : 0.f;
  int   c = (lane < NPART) ? pC[lane] : 0;
#pragma unroll
  for (int off = 32; off > 0; off >>= 1) {
    s += __shfl_down(s, (unsigned)off, 64);
    c += __shfl_down(c, (unsigned)off, 64);
  }
  if (lane == 0) out[0] = s / (float)(c < 1 ? 1 : c);
}

extern "C" void kernel_launch(void* const* d_in, const int* in_sizes, int n_in,
                              void* d_out, int out_size, void* d_ws, size_t ws_size,
                              hipStream_t stream) {
  const float* inputs = (const float*)d_in[0];
  const float* Y      = (const float*)d_in[1];
  const int*   yidx   = (const int*)d_in[2];
  float* out = (float*)d_out;

  char* ws = (char*)d_ws;
  size_t off = 0;
  uint16_t* Ybf    = (uint16_t*)(ws + off); off += (size_t)D_PAD * F_PAD * 2;
  float*    rowSum = (float*)(ws + off);    off += (size_t)N_ROWS * 4;
  int*      rowCnt = (int*)(ws + off);      off += (size_t)N_ROWS * 4;
  uint32_t* subk   = (uint32_t*)(ws + off); off += (size_t)N_ROWS * 8;
  float*    pS     = (float*)(ws + off);    off += (size_t)NPART * 4;
  int*      pC     = (int*)(ws + off);      off += (size_t)NPART * 4;
  off = (off + 255) & ~(size_t)255;
  uint32_t* Spair  = (uint32_t*)(ws + off); off += (size_t)(N_ROWS / 2) * D_PAD * 4;
  const size_t need_mid = off;
  off = (off + 255) & ~(size_t)255;
  uint32_t* keyP   = (uint32_t*)(ws + off); off += (size_t)(N_ROWS / 2) * D_PAD * 4;
  const size_t need_full = off;

  hipLaunchKernelGGL(prep, dim3((D_PAD * F_PAD + 255) / 256), dim3(256),
                     0, stream, Y, Ybf, subk);
  if (ws_size >= need_full) {
    hipLaunchKernelGGL(gemm_kg, dim3(N_ROWS / BM), dim3(KGTHR),
                       0, stream, inputs, Ybf, Spair, keyP, subk);
    hipLaunchKernelGGL(loss_light, dim3(N_ROWS / 8), dim3(256),
                       0, stream, Spair, keyP, yidx, rowSum, rowCnt);
  } else if (ws_size >= need_mid) {
    hipLaunchKernelGGL(gemm_s, dim3(N_ROWS / BM), dim3(GTHR),
                       0, stream, inputs, Ybf, Spair);
    hipLaunchKernelGGL(hash_loss, dim3(N_ROWS / 8), dim3(256),
                       0, stream, Spair, subk, yidx, rowSum, rowCnt);
  } else {
    hipLaunchKernelGGL(triplet_fused, dim3(N_ROWS / M_PB), dim3(NTHR),
                       0, stream, inputs, Ybf, yidx, rowSum, rowCnt);
  }
  hipLaunchKernelGGL(reduce_part, dim3(NPART), dim3(256), 0, stream,
                     rowSum, rowCnt, pS, pC);
  hipLaunchKernelGGL(reduce_final, dim3(1), dim3(64), 0, stream, pS, pC, out);
}